// Round 5
// baseline (722.149 us; speedup 1.0000x reference)
//
#include <hip/hip_runtime.h>
#include <stdint.h>

#define T_ 2048
#define C_ 2048
#define HD 128
#define LDQKV 3072

typedef unsigned short u16;
typedef __attribute__((ext_vector_type(8))) short bf16x8;   // 8 bf16 (4 VGPRs)
typedef __attribute__((ext_vector_type(4))) float f32x4;
typedef __attribute__((ext_vector_type(4))) float float4v;
typedef __attribute__((ext_vector_type(4))) u16 u16x4;
typedef __attribute__((ext_vector_type(8))) u16 u16x8;

typedef __attribute__((address_space(3))) void lds_void;
typedef const __attribute__((address_space(1))) void gbl_void;

__device__ __forceinline__ void gload_lds16(const void* g, void* l) {
  __builtin_amdgcn_global_load_lds((gbl_void*)(uintptr_t)g,
                                   (lds_void*)(uint32_t)(uintptr_t)l, 16, 0, 0);
}

__device__ __forceinline__ u16 f2bf(float f) {
  union { float f; uint32_t u; } v; v.f = f;
  uint32_t r = v.u + 0x7FFFu + ((v.u >> 16) & 1u);
  return (u16)(r >> 16);
}
__device__ __forceinline__ float bf2f(u16 h) {
  union { uint32_t u; float f; } v; v.u = ((uint32_t)h) << 16;
  return v.f;
}

// raw barrier (NOT __syncthreads: that drains vmcnt(0) and kills the pipeline)
#define BAR() do { asm volatile("" ::: "memory"); __builtin_amdgcn_s_barrier(); asm volatile("" ::: "memory"); } while (0)
#define VMCNT(n) asm volatile("s_waitcnt vmcnt(" #n ")" ::: "memory")
#define LGKM0()  asm volatile("s_waitcnt lgkmcnt(0)" ::: "memory")

// ---------- conversions ----------
__global__ __launch_bounds__(256) void k_conv_x(const float* __restrict__ x, u16* __restrict__ o) {
  size_t idx = (size_t)blockIdx.x * 256 + threadIdx.x;
  float4v xv = *(const float4v*)(x + idx * 4);
  u16x4 r;
#pragma unroll
  for (int e = 0; e < 4; ++e) r[e] = f2bf(xv[e]);
  *(u16x4*)(o + idx * 4) = r;
}

// LDS-tiled transpose+convert: out[n][k] = src[k][n], 64x64 tiles
__device__ __forceinline__ void ttile(const float* __restrict__ src, int ldw, int nb,
                                      int k0, int n0out, u16* __restrict__ out, int tid,
                                      float (*Lt)[68]) {
  int kr = tid >> 4, nc = (tid & 15) * 4;
#pragma unroll
  for (int s = 0; s < 4; ++s) {
    float4v v = *(const float4v*)(src + (size_t)(k0 + kr + 16 * s) * ldw + nb + nc);
#pragma unroll
    for (int e = 0; e < 4; ++e) Lt[kr + 16 * s][nc + e] = v[e];
  }
  __syncthreads();
  int nr = tid & 31, kc = (tid >> 5) * 8;
#pragma unroll
  for (int s2 = 0; s2 < 2; ++s2) {
    int n = nr + 32 * s2;
    u16x8 o;
#pragma unroll
    for (int e = 0; e < 8; ++e) o[e] = f2bf(Lt[kc + e][n]);
    *(u16x8*)(out + (size_t)(n0out + n) * 2048 + k0 + kc) = o;
  }
}

__global__ __launch_bounds__(256) void k_wt_qkv(const float* __restrict__ Wq, const float* __restrict__ Wk,
                                                const float* __restrict__ Wv, u16* __restrict__ wt) {
  __shared__ float Lt[64][68];
  const int n0 = blockIdx.x * 64, k0 = blockIdx.y * 64;
  const float* src; int ldw, nb;
  if (n0 < 2048)      { src = Wq; ldw = 2048; nb = n0; }
  else if (n0 < 2560) { src = Wk; ldw = 512;  nb = n0 - 2048; }
  else                { src = Wv; ldw = 512;  nb = n0 - 2560; }
  ttile(src, ldw, nb, k0, n0, wt, threadIdx.x, Lt);
}

__global__ __launch_bounds__(256) void k_wo_t(const float* __restrict__ Wo, u16* __restrict__ wt) {
  __shared__ float Lt[64][68];
  ttile(Wo, 2048, blockIdx.x * 64, blockIdx.y * 64, blockIdx.x * 64, wt, threadIdx.x, Lt);
}

__global__ __launch_bounds__(256) void k_cs(float* __restrict__ cst) {
  int idx = blockIdx.x * 256 + threadIdx.x;   // 131072
  int t = idx >> 6, d = idx & 63;
  float inv = expf(-(float)d * (1.0f / 64.0f) * 9.2103403719761836f);
  float f = (float)t * inv;
  float s, c;
  sincosf(f, &s, &c);
  cst[idx * 2] = c;
  cst[idx * 2 + 1] = s;
}

// RoPE in place, x8 vectorized; folds 1/sqrt(HD) into q heads
__global__ __launch_bounds__(256) void k_rope(u16* __restrict__ qkv, const float* __restrict__ cst) {
  int idx = blockIdx.x * 256 + threadIdx.x;   // 1,310,720
  int token = idx / 160;
  int rem = idx - token * 160;
  int hd = rem >> 3, oct = rem & 7;
  int col = ((hd < 16) ? hd * 128 : 2048 + (hd - 16) * 128) + oct * 8;
  size_t base = (size_t)token * LDQKV + col;
  int t = token & (T_ - 1);
  float sc = (hd < 16) ? 0.08838834764831845f : 1.0f;
  u16x8 a = *(const u16x8*)(qkv + base);
  u16x8 b2 = *(const u16x8*)(qkv + base + 64);
  const float* cp = cst + (size_t)(t * 64 + oct * 8) * 2;
  u16x8 ra, rb;
#pragma unroll
  for (int e = 0; e < 8; ++e) {
    float c = cp[e * 2], s = cp[e * 2 + 1];
    float x1 = bf2f(a[e]), x2 = bf2f(b2[e]);
    ra[e] = f2bf((x1 * c - x2 * s) * sc);
    rb[e] = f2bf((x1 * s + x2 * c) * sc);
  }
  *(u16x8*)(qkv + base) = ra;
  *(u16x8*)(qkv + base + 64) = rb;
}

// ---------- 256x256 pipelined-phase GEMM: C[M][N] = A[M][K] * Bt[N][K]^T ----------
// 8 waves (2M x 4N), BK=64, dbuf LDS 128KB. 4 phases/K-tile, 1 barrier/phase.
// Phase p's MFMA consumes ds_reads issued in phase p-1 (LDS drain overlaps MFMA).
// SYNC RULE (fixes R4 NaN): vmcnt is PER-WAVE; tile data is written by ALL waves'
// DMAs. A region is readable only after: every wave's covering VMCNT -> BARRIER ->
// read in a later phase. Never read in the same phase as the drain.
//   W1 = VMCNT(8) end-ph1 (pre-BAR): drains B(t+1)   [readable ph2+]
//   W2 = VMCNT(4) end-ph2 (pre-BAR): drains A(t+1)   [readable ph3+; also A(t+2)'s
//        af[2-7] reads in next tile's ph0-ph2 are covered by this + barriers]
// Overwrite safety: region's reads always LGKM0-drained + BAR'd before the
// overwriting stage-issue (B(t) last read ph3(t-1); A(t) last read ph2(t)).
#define MQ(Q, BB)                                                             \
  _Pragma("unroll") for (int mi = 0; mi < 2; ++mi)                            \
  _Pragma("unroll") for (int nf = 0; nf < 4; ++nf)                            \
  _Pragma("unroll") for (int ks = 0; ks < 2; ++ks)                            \
      acc[(Q) * 2 + mi][nf] = __builtin_amdgcn_mfma_f32_16x16x32_bf16(        \
          af[(Q) * 2 + mi][ks], BB[nf][ks], acc[(Q) * 2 + mi][nf], 0, 0, 0);

template<int OUTF32>
__global__ __launch_bounds__(512, 2) void k_gemm8(const u16* __restrict__ A, const u16* __restrict__ Bt,
                                                  void* __restrict__ Cout, int M, int N, int K, int nbx) {
  __shared__ __attribute__((aligned(16))) u16 lds[2][2][256 * 64];  // [buf][A/B][row*64+col]
  const int tid = threadIdx.x, lane = tid & 63;
  const int w = tid >> 6, wm = w >> 2, wn = w & 3;
  const int l15 = lane & 15, lhi = lane >> 4;
  const int nwg = gridDim.x, cpx = nwg >> 3;
  const int wg = (blockIdx.x & 7) * cpx + (blockIdx.x >> 3);
  const int bx = wg % nbx, by = wg / nbx;
  const int m0 = by * 256, n0 = bx * 256;
  const int NT = K >> 6;

  auto STAGE = [&](int half, int tt) {   // half: 0=A0,1=A1,2=B0,3=B1 ; 2 loads/wave-thread
    const u16* src = (half < 2) ? A : Bt;
    const int r0 = ((half < 2) ? m0 : n0) + (half & 1) * 128;
    u16* dst = &lds[tt & 1][half >> 1][(half & 1) * 8192];
    const int kk = tt * 64;
#pragma unroll
    for (int it = 0; it < 2; ++it) {
      int c = it * 512 + tid;
      int row = c >> 3, kc = c & 7;
      gload_lds16(src + (size_t)(r0 + row) * K + kk + ((kc ^ (row & 7)) * 8), dst + c * 8);
    }
  };
  auto RA = [&](const u16* buf, int mf, int ks) -> bf16x8 {
    return *(const bf16x8*)&buf[(wm * 128 + mf * 16 + l15) * 64 + (((ks * 4 + lhi) ^ (l15 & 7)) * 8)];
  };
  auto RB = [&](const u16* buf, int nf, int ks) -> bf16x8 {
    return *(const bf16x8*)&buf[(wn * 64 + nf * 16 + l15) * 64 + (((ks * 4 + lhi) ^ (l15 & 7)) * 8)];
  };

  f32x4 acc[8][4];
#pragma unroll
  for (int i = 0; i < 8; ++i)
#pragma unroll
    for (int j = 0; j < 4; ++j) acc[i][j] = (f32x4){0.f, 0.f, 0.f, 0.f};

  bf16x8 af[8][2], bbA[4][2], bbB[4][2];

  // prologue: stage tile0 + tile1; drain OWN tile0 loads; BARRIER (=> tile0 globally
  // valid); then the "ph3(-1)" reads; drain reads; BARRIER (=> safe to overwrite B0).
  STAGE(0, 0); STAGE(1, 0); STAGE(2, 0); STAGE(3, 0);
  STAGE(2, 1); STAGE(3, 1); STAGE(0, 1); STAGE(1, 1);
  VMCNT(8);
  BAR();
#pragma unroll
  for (int ks = 0; ks < 2; ++ks) {
    af[0][ks] = RA(lds[0][0], 0, ks);
    af[1][ks] = RA(lds[0][0], 1, ks);
#pragma unroll
    for (int nf = 0; nf < 4; ++nf) bbA[nf][ks] = RB(lds[0][1], nf, ks);
  }
  LGKM0();
  BAR();

  auto TILE = [&](int t, bf16x8 (&bbc)[4][2], bf16x8 (&bbn)[4][2]) {
    const u16* Ac = lds[t & 1][0];
    const u16* An = lds[(t + 1) & 1][0];
    const u16* Bn = lds[(t + 1) & 1][1];
    const bool hasN1 = (t + 1 < NT), hasN2 = (t + 2 < NT);
    // ---- ph0: stage B0(t+2); read af[2-3](t); MFMA Q0
    if (hasN2) STAGE(2, t + 2);
#pragma unroll
    for (int ks = 0; ks < 2; ++ks) { af[2][ks] = RA(Ac, 2, ks); af[3][ks] = RA(Ac, 3, ks); }
    __builtin_amdgcn_s_setprio(1);
    MQ(0, bbc);
    __builtin_amdgcn_s_setprio(0);
    LGKM0(); BAR();
    // ---- ph1: stage B1(t+2); read af[4-5](t); MFMA Q1; W1 drains B(t+1)
    if (hasN2) STAGE(3, t + 2);
#pragma unroll
    for (int ks = 0; ks < 2; ++ks) { af[4][ks] = RA(Ac, 4, ks); af[5][ks] = RA(Ac, 5, ks); }
    __builtin_amdgcn_s_setprio(1);
    MQ(1, bbc);
    __builtin_amdgcn_s_setprio(0);
    LGKM0();
    if (hasN2) { VMCNT(8); } else { VMCNT(0); }
    BAR();
    // ---- ph2: read af[6-7](t) + bbn[0-1](t+1); MFMA Q2; W2 drains A(t+1)
#pragma unroll
    for (int ks = 0; ks < 2; ++ks) { af[6][ks] = RA(Ac, 6, ks); af[7][ks] = RA(Ac, 7, ks); }
    if (hasN1) {
#pragma unroll
      for (int ks = 0; ks < 2; ++ks) { bbn[0][ks] = RB(Bn, 0, ks); bbn[1][ks] = RB(Bn, 1, ks); }
    }
    __builtin_amdgcn_s_setprio(1);
    MQ(2, bbc);
    __builtin_amdgcn_s_setprio(0);
    LGKM0();
    if (hasN2) { VMCNT(4); } else { VMCNT(0); }
    BAR();
    // ---- ph3: stage A0,A1(t+2); read af[0-1](t+1) + bbn[2-3](t+1); MFMA Q3
    if (hasN2) { STAGE(0, t + 2); STAGE(1, t + 2); }
    if (hasN1) {
#pragma unroll
      for (int ks = 0; ks < 2; ++ks) {
        af[0][ks] = RA(An, 0, ks); af[1][ks] = RA(An, 1, ks);
        bbn[2][ks] = RB(Bn, 2, ks); bbn[3][ks] = RB(Bn, 3, ks);
      }
    }
    __builtin_amdgcn_s_setprio(1);
    MQ(3, bbc);
    __builtin_amdgcn_s_setprio(0);
    LGKM0(); BAR();
  };

  for (int tp = 0; tp < NT; tp += 2) {
    TILE(tp, bbA, bbB);
    TILE(tp + 1, bbB, bbA);
  }

  // epilogue: rows m0+wm*128+mf*16+lhi*4+r, cols n0+wn*64+nf*16+l15
#pragma unroll
  for (int mf = 0; mf < 8; ++mf) {
#pragma unroll
    for (int nf = 0; nf < 4; ++nf) {
      int col = n0 + wn * 64 + nf * 16 + l15;
#pragma unroll
      for (int r = 0; r < 4; ++r) {
        int row = m0 + wm * 128 + mf * 16 + lhi * 4 + r;
        float v = acc[mf][nf][r];
        if (OUTF32) ((float*)Cout)[(size_t)row * N + col] = v;
        else        ((u16*)Cout)[(size_t)row * N + col] = f2bf(v);
      }
    }
  }
}

// ---------- windowed flash attention (swizzled, conflict-free; unchanged from R3) ----------
__global__ __launch_bounds__(256) void k_attn(const u16* __restrict__ qkv, u16* __restrict__ y) {
  const int bid = blockIdx.x;
  const int qt = bid & 31, h = (bid >> 5) & 15, b = bid >> 9;
  const int i0 = qt * 64;
  const size_t tb = (size_t)b * T_ * LDQKV;
  const u16* qb = qkv + tb + h * HD;
  const u16* kb = qkv + tb + 2048 + (h >> 2) * HD;
  const u16* vb = kb + 512;
  __shared__ __attribute__((aligned(16))) u16 smem[20480];   // 40 KB
  u16* Ks = smem;
  u16* Vt = smem + 8192;
  u16* Psw = smem + 16384;
  u16* Qs = smem;
  const int tid = threadIdx.x, lane = tid & 63, w = tid >> 6;
  const int l15 = lane & 15, lhi = lane >> 4;
  u16* Ps = Psw + w * 1024;

#pragma unroll
  for (int it = 0; it < 4; ++it) {
    int c = it * 256 + tid, row = c >> 4, kc = (c & 15) ^ (row & 7);
    gload_lds16(qb + (size_t)(i0 + row) * LDQKV + kc * 8, &Qs[(it * 256 + w * 64) * 8]);
  }
  __syncthreads();
  bf16x8 qf[4];
#pragma unroll
  for (int ks = 0; ks < 4; ++ks) {
    int row = w * 16 + l15;
    int kc = (ks * 4 + lhi) ^ (row & 7);
    qf[ks] = *(const bf16x8*)&Qs[(row * 16 + kc) * 8];
  }
  __syncthreads();

  f32x4 o[8];
#pragma unroll
  for (int dt = 0; dt < 8; ++dt) o[dt] = (f32x4){0.f, 0.f, 0.f, 0.f};
  float mrun[4], lrun[4];
#pragma unroll
  for (int r = 0; r < 4; ++r) { mrun[r] = -1e30f; lrun[r] = 0.f; }

  const int jb0 = (i0 >= 256) ? (i0 - 256) : 0;
  for (int jb = jb0; jb <= i0; jb += 64) {
#pragma unroll
    for (int it = 0; it < 4; ++it) {
      int c = it * 256 + tid, row = c >> 4, kc = (c & 15) ^ (row & 7);
      gload_lds16(kb + (size_t)(jb + row) * LDQKV + kc * 8, &Ks[(it * 256 + w * 64) * 8]);
    }
#pragma unroll
    for (int it = 0; it < 4; ++it) {
      int chunk = it * 256 + tid, row = chunk >> 4, dc = chunk & 15;
      u16x8 vv = *(const u16x8*)(vb + (size_t)(jb + row) * LDQKV + dc * 8);
#pragma unroll
      for (int e = 0; e < 8; ++e) {
        int d = dc * 8 + e;
        int s = (dc ^ e) & 7;
        Vt[d * 64 + (row ^ (s << 3))] = vv[e];
      }
    }
    __syncthreads();

    f32x4 s[4];
#pragma unroll
    for (int t = 0; t < 4; ++t) {
      s[t] = (f32x4){0.f, 0.f, 0.f, 0.f};
#pragma unroll
      for (int ks = 0; ks < 4; ++ks) {
        int row = t * 16 + l15;
        int kc = (ks * 4 + lhi) ^ (row & 7);
        bf16x8 kf = *(const bf16x8*)&Ks[(row * 16 + kc) * 8];
        s[t] = __builtin_amdgcn_mfma_f32_16x16x32_bf16(qf[ks], kf, s[t], 0, 0, 0);
      }
    }

    const int irow0 = i0 + w * 16 + lhi * 4;
    float rmax[4];
#pragma unroll
    for (int r = 0; r < 4; ++r) rmax[r] = -1e30f;
#pragma unroll
    for (int t = 0; t < 4; ++t) {
      int j = jb + t * 16 + l15;
#pragma unroll
      for (int r = 0; r < 4; ++r) {
        int i = irow0 + r;
        float sv = s[t][r];
        sv = (j <= i && j + 256 >= i) ? sv : -1e30f;
        s[t][r] = sv;
        rmax[r] = fmaxf(rmax[r], sv);
      }
    }
#pragma unroll
    for (int r = 0; r < 4; ++r) {
#pragma unroll
      for (int off = 1; off < 16; off <<= 1)
        rmax[r] = fmaxf(rmax[r], __shfl_xor(rmax[r], off));
    }
    float sf[4], psum[4];
#pragma unroll
    for (int r = 0; r < 4; ++r) {
      float mn = fmaxf(mrun[r], rmax[r]);
      sf[r] = __expf(mrun[r] - mn);
      mrun[r] = mn;
      psum[r] = 0.f;
    }
#pragma unroll
    for (int t = 0; t < 4; ++t) {
#pragma unroll
      for (int r = 0; r < 4; ++r) {
        float p = __expf(s[t][r] - mrun[r]);
        psum[r] += p;
        int q = lhi * 4 + r;
        int k = t * 16 + l15;
        Ps[q * 64 + (k ^ ((q & 7) << 3))] = f2bf(p);
      }
    }
#pragma unroll
    for (int r = 0; r < 4; ++r) {
#pragma unroll
      for (int off = 1; off < 16; off <<= 1)
        psum[r] += __shfl_xor(psum[r], off);
      lrun[r] = lrun[r] * sf[r] + psum[r];
    }
#pragma unroll
    for (int dt = 0; dt < 8; ++dt)
#pragma unroll
      for (int r = 0; r < 4; ++r)
        o[dt][r] = o[dt][r] * sf[r];

    bf16x8 pf[2];
#pragma unroll
    for (int ks2 = 0; ks2 < 2; ++ks2)
      pf[ks2] = *(const bf16x8*)&Ps[l15 * 64 + ((ks2 * 32 + lhi * 8) ^ ((l15 & 7) << 3))];
#pragma unroll
    for (int dt = 0; dt < 8; ++dt) {
#pragma unroll
      for (int ks2 = 0; ks2 < 2; ++ks2) {
        int d = dt * 16 + l15;
        int s2 = ((d >> 3) ^ (d & 7)) & 7;
        bf16x8 vf = *(const bf16x8*)&Vt[d * 64 + ((ks2 * 32 + lhi * 8) ^ (s2 << 3))];
        o[dt] = __builtin_amdgcn_mfma_f32_16x16x32_bf16(pf[ks2], vf, o[dt], 0, 0, 0);
      }
    }
    __syncthreads();
  }

#pragma unroll
  for (int dt = 0; dt < 8; ++dt) {
#pragma unroll
    for (int r = 0; r < 4; ++r) {
      int i = i0 + w * 16 + lhi * 4 + r;
      float v = o[dt][r] / lrun[r];
      y[((size_t)b * T_ + i) * C_ + h * HD + dt * 16 + l15] = f2bf(v);
    }
  }
}

extern "C" void kernel_launch(void* const* d_in, const int* in_sizes, int n_in,
                              void* d_out, int out_size, void* d_ws, size_t ws_size,
                              hipStream_t stream) {
  const float* x  = (const float*)d_in[0];
  const float* Wq = (const float*)d_in[1];
  const float* Wk = (const float*)d_in[2];
  const float* Wv = (const float*)d_in[3];
  const float* Wo = (const float*)d_in[4];
  char* ws = (char*)d_ws;
  u16* x_bf   = (u16*)(ws);                 // 33,554,432 B (reused as y after GEMM1)
  u16* wt_qkv = (u16*)(ws + 33554432);      // 12,582,912 B
  u16* wo_t   = (u16*)(ws + 46137344);      //  8,388,608 B
  u16* qkv    = (u16*)(ws + 54525952);      // 50,331,648 B
  float* cst  = (float*)(ws + 104857600);   //  1,048,576 B
  u16* ybuf = x_bf;

  k_conv_x <<<16384, 256, 0, stream>>>(x, x_bf);
  k_wt_qkv <<<dim3(48, 32), 256, 0, stream>>>(Wq, Wk, Wv, wt_qkv);
  k_wo_t   <<<dim3(32, 32), 256, 0, stream>>>(Wo, wo_t);
  k_cs     <<<512, 256, 0, stream>>>(cst);

  k_gemm8<0><<<384, 512, 0, stream>>>(x_bf, wt_qkv, (void*)qkv, 8192, 3072, 2048, 12);

  k_rope   <<<5120, 256, 0, stream>>>(qkv, cst);
  k_attn   <<<2048, 256, 0, stream>>>(qkv, ybuf);

  k_gemm8<1><<<256, 512, 0, stream>>>(ybuf, wo_t, d_out, 8192, 2048, 2048, 8);
}

// Round 6
// 313.731 us; speedup vs baseline: 2.3018x; 2.3018x over previous
//
#include <hip/hip_runtime.h>
#include <stdint.h>

#define T_ 2048
#define C_ 2048
#define HD 128
#define LDQKV 3072

typedef unsigned short u16;
typedef __attribute__((ext_vector_type(8))) short bf16x8;   // 8 bf16 (4 VGPRs)
typedef __attribute__((ext_vector_type(4))) float f32x4;
typedef __attribute__((ext_vector_type(4))) float float4v;
typedef __attribute__((ext_vector_type(4))) u16 u16x4;
typedef __attribute__((ext_vector_type(8))) u16 u16x8;

typedef __attribute__((address_space(3))) void lds_void;
typedef const __attribute__((address_space(1))) void gbl_void;

__device__ __forceinline__ void gload_lds16(const void* g, void* l) {
  __builtin_amdgcn_global_load_lds((gbl_void*)(uintptr_t)g,
                                   (lds_void*)(uint32_t)(uintptr_t)l, 16, 0, 0);
}

__device__ __forceinline__ u16 f2bf(float f) {
  union { float f; uint32_t u; } v; v.f = f;
  uint32_t r = v.u + 0x7FFFu + ((v.u >> 16) & 1u);
  return (u16)(r >> 16);
}
__device__ __forceinline__ float bf2f(u16 h) {
  union { uint32_t u; float f; } v; v.u = ((uint32_t)h) << 16;
  return v.f;
}

// raw barrier (NOT __syncthreads: that drains vmcnt(0) and kills the pipeline)
#define BAR() do { asm volatile("" ::: "memory"); __builtin_amdgcn_s_barrier(); asm volatile("" ::: "memory"); } while (0)
#define VMCNT(n) asm volatile("s_waitcnt vmcnt(" #n ")" ::: "memory")
#define LGKM0()  asm volatile("s_waitcnt lgkmcnt(0)" ::: "memory")

// ---------- conversions ----------
__global__ __launch_bounds__(256) void k_conv_x(const float* __restrict__ x, u16* __restrict__ o) {
  size_t idx = (size_t)blockIdx.x * 256 + threadIdx.x;
  float4v xv = *(const float4v*)(x + idx * 4);
  u16x4 r;
#pragma unroll
  for (int e = 0; e < 4; ++e) r[e] = f2bf(xv[e]);
  *(u16x4*)(o + idx * 4) = r;
}

// LDS-tiled transpose+convert: out[n][k] = src[k][n], 64x64 tiles
__device__ __forceinline__ void ttile(const float* __restrict__ src, int ldw, int nb,
                                      int k0, int n0out, u16* __restrict__ out, int tid,
                                      float (*Lt)[68]) {
  int kr = tid >> 4, nc = (tid & 15) * 4;
#pragma unroll
  for (int s = 0; s < 4; ++s) {
    float4v v = *(const float4v*)(src + (size_t)(k0 + kr + 16 * s) * ldw + nb + nc);
#pragma unroll
    for (int e = 0; e < 4; ++e) Lt[kr + 16 * s][nc + e] = v[e];
  }
  __syncthreads();
  int nr = tid & 31, kc = (tid >> 5) * 8;
#pragma unroll
  for (int s2 = 0; s2 < 2; ++s2) {
    int n = nr + 32 * s2;
    u16x8 o;
#pragma unroll
    for (int e = 0; e < 8; ++e) o[e] = f2bf(Lt[kc + e][n]);
    *(u16x8*)(out + (size_t)(n0out + n) * 2048 + k0 + kc) = o;
  }
}

__global__ __launch_bounds__(256) void k_wt_qkv(const float* __restrict__ Wq, const float* __restrict__ Wk,
                                                const float* __restrict__ Wv, u16* __restrict__ wt) {
  __shared__ float Lt[64][68];
  const int n0 = blockIdx.x * 64, k0 = blockIdx.y * 64;
  const float* src; int ldw, nb;
  if (n0 < 2048)      { src = Wq; ldw = 2048; nb = n0; }
  else if (n0 < 2560) { src = Wk; ldw = 512;  nb = n0 - 2048; }
  else                { src = Wv; ldw = 512;  nb = n0 - 2560; }
  ttile(src, ldw, nb, k0, n0, wt, threadIdx.x, Lt);
}

__global__ __launch_bounds__(256) void k_wo_t(const float* __restrict__ Wo, u16* __restrict__ wt) {
  __shared__ float Lt[64][68];
  ttile(Wo, 2048, blockIdx.x * 64, blockIdx.y * 64, blockIdx.x * 64, wt, threadIdx.x, Lt);
}

__global__ __launch_bounds__(256) void k_cs(float* __restrict__ cst) {
  int idx = blockIdx.x * 256 + threadIdx.x;   // 131072
  int t = idx >> 6, d = idx & 63;
  float inv = expf(-(float)d * (1.0f / 64.0f) * 9.2103403719761836f);
  float f = (float)t * inv;
  float s, c;
  sincosf(f, &s, &c);
  cst[idx * 2] = c;
  cst[idx * 2 + 1] = s;
}

// RoPE in place, x8 vectorized; folds 1/sqrt(HD) into q heads
__global__ __launch_bounds__(256) void k_rope(u16* __restrict__ qkv, const float* __restrict__ cst) {
  int idx = blockIdx.x * 256 + threadIdx.x;   // 1,310,720
  int token = idx / 160;
  int rem = idx - token * 160;
  int hd = rem >> 3, oct = rem & 7;
  int col = ((hd < 16) ? hd * 128 : 2048 + (hd - 16) * 128) + oct * 8;
  size_t base = (size_t)token * LDQKV + col;
  int t = token & (T_ - 1);
  float sc = (hd < 16) ? 0.08838834764831845f : 1.0f;
  u16x8 a = *(const u16x8*)(qkv + base);
  u16x8 b2 = *(const u16x8*)(qkv + base + 64);
  const float* cp = cst + (size_t)(t * 64 + oct * 8) * 2;
  u16x8 ra, rb;
#pragma unroll
  for (int e = 0; e < 8; ++e) {
    float c = cp[e * 2], s = cp[e * 2 + 1];
    float x1 = bf2f(a[e]), x2 = bf2f(b2[e]);
    ra[e] = f2bf((x1 * c - x2 * s) * sc);
    rb[e] = f2bf((x1 * s + x2 * c) * sc);
  }
  *(u16x8*)(qkv + base) = ra;
  *(u16x8*)(qkv + base + 64) = rb;
}

// ---------- 256x256 8-phase GEMM (m201-faithful): C[M][N] = A[M][K] * Bt[N][K]^T ----------
// 8 waves (2M x 4N), BK=64, dbuf LDS 128KB -> 1 block/CU, so __launch_bounds__(512,1)
// (R5 lesson: min-waves=2 capped VGPR at 128 -> acc(128)+frags spilled -> 3x slower).
// Per phase (m201 template): {ds_read operand subtile; stage issue; BAR; lgkmcnt(0);
// setprio(1); 16 MFMA; setprio(0); BAR}. Operands consumed in the SAME phase ->
// per-phase register lifetime small (acc 128 + bb 16 + aa 8).
// Staging stagger (FIFO-verified): A0(t+1)@ph0, A1(t+1)@ph1, B0(t+2)@ph2, B1(t+2)@ph3.
// VMCNT(4) at ph3 pre-BAR: queue = [B(t+1):4][A(t+1):4][B(t+2):4] -> drains t+1
// fully, leaves B(t+2) in flight. Tail: VMCNT(0) when t+2>=NT.
// Overwrite safety: B(t) LDS free after ph0's closing BAR (bb drained at ph0 LGKM0);
// stage B(t+2)->same region at ph2 OK. A(t+1) goes to the other buffer, whose A was
// last read at t-1 ph3 (drained pre-barrier) -> stage at t ph0 OK.
#define MQ(Q)                                                                 \
  _Pragma("unroll") for (int mi = 0; mi < 2; ++mi)                            \
  _Pragma("unroll") for (int nf = 0; nf < 4; ++nf)                            \
  _Pragma("unroll") for (int ks = 0; ks < 2; ++ks)                            \
      acc[(Q) * 2 + mi][nf] = __builtin_amdgcn_mfma_f32_16x16x32_bf16(        \
          aa[mi][ks], bb[nf][ks], acc[(Q) * 2 + mi][nf], 0, 0, 0);

template<int OUTF32>
__global__ __launch_bounds__(512, 1) void k_gemm8(const u16* __restrict__ A, const u16* __restrict__ Bt,
                                                  void* __restrict__ Cout, int M, int N, int K, int nbx) {
  __shared__ __attribute__((aligned(16))) u16 lds[2][2][256 * 64];  // [buf][A/B][row*64+col]
  const int tid = threadIdx.x, lane = tid & 63;
  const int w = tid >> 6, wm = w >> 2, wn = w & 3;
  const int l15 = lane & 15, lhi = lane >> 4;
  const int nwg = gridDim.x, cpx = nwg >> 3;
  const int wg = (blockIdx.x & 7) * cpx + (blockIdx.x >> 3);
  const int bx = wg % nbx, by = wg / nbx;
  const int m0 = by * 256, n0 = bx * 256;
  const int NT = K >> 6;

  auto STAGE = [&](int half, int tt) {   // half: 0=A0,1=A1,2=B0,3=B1 ; 2 loads/thread
    const u16* src = (half < 2) ? A : Bt;
    const int r0 = ((half < 2) ? m0 : n0) + (half & 1) * 128;
    u16* dst = &lds[tt & 1][half >> 1][(half & 1) * 8192];
    const int kk = tt * 64;
#pragma unroll
    for (int it = 0; it < 2; ++it) {
      int c = it * 512 + tid;
      int row = c >> 3, kc = c & 7;
      gload_lds16(src + (size_t)(r0 + row) * K + kk + ((kc ^ (row & 7)) * 8), dst + c * 8);
    }
  };
  auto RA = [&](const u16* buf, int mf, int ks) -> bf16x8 {
    return *(const bf16x8*)&buf[(wm * 128 + mf * 16 + l15) * 64 + (((ks * 4 + lhi) ^ (l15 & 7)) * 8)];
  };
  auto RB = [&](const u16* buf, int nf, int ks) -> bf16x8 {
    return *(const bf16x8*)&buf[(wn * 64 + nf * 16 + l15) * 64 + (((ks * 4 + lhi) ^ (l15 & 7)) * 8)];
  };

  f32x4 acc[8][4];
#pragma unroll
  for (int i = 0; i < 8; ++i)
#pragma unroll
    for (int j = 0; j < 4; ++j) acc[i][j] = (f32x4){0.f, 0.f, 0.f, 0.f};

  // prologue: tile0 (4 halves) + B(t1) (2 halves) = steady-state entry invariant
  STAGE(0, 0); STAGE(1, 0); STAGE(2, 0); STAGE(3, 0);
  STAGE(2, 1); STAGE(3, 1);
  VMCNT(4);   // drain tile0, leave B(t1)'s 4 in flight
  BAR();

  for (int t = 0; t < NT; ++t) {
    const u16* Ab = lds[t & 1][0];
    const u16* Bb = lds[t & 1][1];
    const bool hasN1 = (t + 1 < NT), hasN2 = (t + 2 < NT);
    bf16x8 bb[4][2], aa[2][2];
    // ---- ph0: read bb(8) + af[0-1](4); stage A0(t+1)
#pragma unroll
    for (int nf = 0; nf < 4; ++nf) { bb[nf][0] = RB(Bb, nf, 0); bb[nf][1] = RB(Bb, nf, 1); }
#pragma unroll
    for (int ks = 0; ks < 2; ++ks) { aa[0][ks] = RA(Ab, 0, ks); aa[1][ks] = RA(Ab, 1, ks); }
    if (hasN1) STAGE(0, t + 1);
    BAR(); LGKM0();
    __builtin_amdgcn_s_setprio(1);
    MQ(0);
    __builtin_amdgcn_s_setprio(0);
    BAR();
    // ---- ph1: read af[2-3]; stage A1(t+1)
#pragma unroll
    for (int ks = 0; ks < 2; ++ks) { aa[0][ks] = RA(Ab, 2, ks); aa[1][ks] = RA(Ab, 3, ks); }
    if (hasN1) STAGE(1, t + 1);
    BAR(); LGKM0();
    __builtin_amdgcn_s_setprio(1);
    MQ(1);
    __builtin_amdgcn_s_setprio(0);
    BAR();
    // ---- ph2: read af[4-5]; stage B0(t+2) (B(t) region free since ph0 close)
#pragma unroll
    for (int ks = 0; ks < 2; ++ks) { aa[0][ks] = RA(Ab, 4, ks); aa[1][ks] = RA(Ab, 5, ks); }
    if (hasN2) STAGE(2, t + 2);
    BAR(); LGKM0();
    __builtin_amdgcn_s_setprio(1);
    MQ(2);
    __builtin_amdgcn_s_setprio(0);
    BAR();
    // ---- ph3: read af[6-7]; stage B1(t+2); counted vmcnt then barrier
#pragma unroll
    for (int ks = 0; ks < 2; ++ks) { aa[0][ks] = RA(Ab, 6, ks); aa[1][ks] = RA(Ab, 7, ks); }
    if (hasN2) STAGE(3, t + 2);
    BAR(); LGKM0();
    __builtin_amdgcn_s_setprio(1);
    MQ(3);
    __builtin_amdgcn_s_setprio(0);
    if (hasN2) { VMCNT(4); } else { VMCNT(0); }
    BAR();
  }

  // epilogue: rows m0+wm*128+mf*16+lhi*4+r, cols n0+wn*64+nf*16+l15
#pragma unroll
  for (int mf = 0; mf < 8; ++mf) {
#pragma unroll
    for (int nf = 0; nf < 4; ++nf) {
      int col = n0 + wn * 64 + nf * 16 + l15;
#pragma unroll
      for (int r = 0; r < 4; ++r) {
        int row = m0 + wm * 128 + mf * 16 + lhi * 4 + r;
        float v = acc[mf][nf][r];
        if (OUTF32) ((float*)Cout)[(size_t)row * N + col] = v;
        else        ((u16*)Cout)[(size_t)row * N + col] = f2bf(v);
      }
    }
  }
}

// ---------- windowed flash attention (swizzled, conflict-free; unchanged) ----------
__global__ __launch_bounds__(256) void k_attn(const u16* __restrict__ qkv, u16* __restrict__ y) {
  const int bid = blockIdx.x;
  const int qt = bid & 31, h = (bid >> 5) & 15, b = bid >> 9;
  const int i0 = qt * 64;
  const size_t tb = (size_t)b * T_ * LDQKV;
  const u16* qb = qkv + tb + h * HD;
  const u16* kb = qkv + tb + 2048 + (h >> 2) * HD;
  const u16* vb = kb + 512;
  __shared__ __attribute__((aligned(16))) u16 smem[20480];   // 40 KB
  u16* Ks = smem;
  u16* Vt = smem + 8192;
  u16* Psw = smem + 16384;
  u16* Qs = smem;
  const int tid = threadIdx.x, lane = tid & 63, w = tid >> 6;
  const int l15 = lane & 15, lhi = lane >> 4;
  u16* Ps = Psw + w * 1024;

#pragma unroll
  for (int it = 0; it < 4; ++it) {
    int c = it * 256 + tid, row = c >> 4, kc = (c & 15) ^ (row & 7);
    gload_lds16(qb + (size_t)(i0 + row) * LDQKV + kc * 8, &Qs[(it * 256 + w * 64) * 8]);
  }
  __syncthreads();
  bf16x8 qf[4];
#pragma unroll
  for (int ks = 0; ks < 4; ++ks) {
    int row = w * 16 + l15;
    int kc = (ks * 4 + lhi) ^ (row & 7);
    qf[ks] = *(const bf16x8*)&Qs[(row * 16 + kc) * 8];
  }
  __syncthreads();

  f32x4 o[8];
#pragma unroll
  for (int dt = 0; dt < 8; ++dt) o[dt] = (f32x4){0.f, 0.f, 0.f, 0.f};
  float mrun[4], lrun[4];
#pragma unroll
  for (int r = 0; r < 4; ++r) { mrun[r] = -1e30f; lrun[r] = 0.f; }

  const int jb0 = (i0 >= 256) ? (i0 - 256) : 0;
  for (int jb = jb0; jb <= i0; jb += 64) {
#pragma unroll
    for (int it = 0; it < 4; ++it) {
      int c = it * 256 + tid, row = c >> 4, kc = (c & 15) ^ (row & 7);
      gload_lds16(kb + (size_t)(jb + row) * LDQKV + kc * 8, &Ks[(it * 256 + w * 64) * 8]);
    }
#pragma unroll
    for (int it = 0; it < 4; ++it) {
      int chunk = it * 256 + tid, row = chunk >> 4, dc = chunk & 15;
      u16x8 vv = *(const u16x8*)(vb + (size_t)(jb + row) * LDQKV + dc * 8);
#pragma unroll
      for (int e = 0; e < 8; ++e) {
        int d = dc * 8 + e;
        int s = (dc ^ e) & 7;
        Vt[d * 64 + (row ^ (s << 3))] = vv[e];
      }
    }
    __syncthreads();

    f32x4 s[4];
#pragma unroll
    for (int t = 0; t < 4; ++t) {
      s[t] = (f32x4){0.f, 0.f, 0.f, 0.f};
#pragma unroll
      for (int ks = 0; ks < 4; ++ks) {
        int row = t * 16 + l15;
        int kc = (ks * 4 + lhi) ^ (row & 7);
        bf16x8 kf = *(const bf16x8*)&Ks[(row * 16 + kc) * 8];
        s[t] = __builtin_amdgcn_mfma_f32_16x16x32_bf16(qf[ks], kf, s[t], 0, 0, 0);
      }
    }

    const int irow0 = i0 + w * 16 + lhi * 4;
    float rmax[4];
#pragma unroll
    for (int r = 0; r < 4; ++r) rmax[r] = -1e30f;
#pragma unroll
    for (int t = 0; t < 4; ++t) {
      int j = jb + t * 16 + l15;
#pragma unroll
      for (int r = 0; r < 4; ++r) {
        int i = irow0 + r;
        float sv = s[t][r];
        sv = (j <= i && j + 256 >= i) ? sv : -1e30f;
        s[t][r] = sv;
        rmax[r] = fmaxf(rmax[r], sv);
      }
    }
#pragma unroll
    for (int r = 0; r < 4; ++r) {
#pragma unroll
      for (int off = 1; off < 16; off <<= 1)
        rmax[r] = fmaxf(rmax[r], __shfl_xor(rmax[r], off));
    }
    float sf[4], psum[4];
#pragma unroll
    for (int r = 0; r < 4; ++r) {
      float mn = fmaxf(mrun[r], rmax[r]);
      sf[r] = __expf(mrun[r] - mn);
      mrun[r] = mn;
      psum[r] = 0.f;
    }
#pragma unroll
    for (int t = 0; t < 4; ++t) {
#pragma unroll
      for (int r = 0; r < 4; ++r) {
        float p = __expf(s[t][r] - mrun[r]);
        psum[r] += p;
        int q = lhi * 4 + r;
        int k = t * 16 + l15;
        Ps[q * 64 + (k ^ ((q & 7) << 3))] = f2bf(p);
      }
    }
#pragma unroll
    for (int r = 0; r < 4; ++r) {
#pragma unroll
      for (int off = 1; off < 16; off <<= 1)
        psum[r] += __shfl_xor(psum[r], off);
      lrun[r] = lrun[r] * sf[r] + psum[r];
    }
#pragma unroll
    for (int dt = 0; dt < 8; ++dt)
#pragma unroll
      for (int r = 0; r < 4; ++r)
        o[dt][r] = o[dt][r] * sf[r];

    bf16x8 pf[2];
#pragma unroll
    for (int ks2 = 0; ks2 < 2; ++ks2)
      pf[ks2] = *(const bf16x8*)&Ps[l15 * 64 + ((ks2 * 32 + lhi * 8) ^ ((l15 & 7) << 3))];
#pragma unroll
    for (int dt = 0; dt < 8; ++dt) {
#pragma unroll
      for (int ks2 = 0; ks2 < 2; ++ks2) {
        int d = dt * 16 + l15;
        int s2 = ((d >> 3) ^ (d & 7)) & 7;
        bf16x8 vf = *(const bf16x8*)&Vt[d * 64 + ((ks2 * 32 + lhi * 8) ^ (s2 << 3))];
        o[dt] = __builtin_amdgcn_mfma_f32_16x16x32_bf16(pf[ks2], vf, o[dt], 0, 0, 0);
      }
    }
    __syncthreads();
  }

#pragma unroll
  for (int dt = 0; dt < 8; ++dt) {
#pragma unroll
    for (int r = 0; r < 4; ++r) {
      int i = i0 + w * 16 + lhi * 4 + r;
      float v = o[dt][r] / lrun[r];
      y[((size_t)b * T_ + i) * C_ + h * HD + dt * 16 + l15] = f2bf(v);
    }
  }
}

extern "C" void kernel_launch(void* const* d_in, const int* in_sizes, int n_in,
                              void* d_out, int out_size, void* d_ws, size_t ws_size,
                              hipStream_t stream) {
  const float* x  = (const float*)d_in[0];
  const float* Wq = (const float*)d_in[1];
  const float* Wk = (const float*)d_in[2];
  const float* Wv = (const float*)d_in[3];
  const float* Wo = (const float*)d_in[4];
  char* ws = (char*)d_ws;
  u16* x_bf   = (u16*)(ws);                 // 33,554,432 B (reused as y after GEMM1)
  u16* wt_qkv = (u16*)(ws + 33554432);      // 12,582,912 B
  u16* wo_t   = (u16*)(ws + 46137344);      //  8,388,608 B
  u16* qkv    = (u16*)(ws + 54525952);      // 50,331,648 B
  float* cst  = (float*)(ws + 104857600);   //  1,048,576 B
  u16* ybuf = x_bf;

  k_conv_x <<<16384, 256, 0, stream>>>(x, x_bf);
  k_wt_qkv <<<dim3(48, 32), 256, 0, stream>>>(Wq, Wk, Wv, wt_qkv);
  k_wo_t   <<<dim3(32, 32), 256, 0, stream>>>(Wo, wo_t);
  k_cs     <<<512, 256, 0, stream>>>(cst);

  k_gemm8<0><<<384, 512, 0, stream>>>(x_bf, wt_qkv, (void*)qkv, 8192, 3072, 2048, 12);

  k_rope   <<<5120, 256, 0, stream>>>(qkv, cst);
  k_attn   <<<2048, 256, 0, stream>>>(qkv, ybuf);

  k_gemm8<1><<<256, 512, 0, stream>>>(ybuf, wo_t, d_out, 8192, 2048, 2048, 8);
}

// Round 7
// 297.038 us; speedup vs baseline: 2.4312x; 1.0562x over previous
//
#include <hip/hip_runtime.h>
#include <stdint.h>

#define T_ 2048
#define C_ 2048
#define HD 128
#define LDQKV 3072

typedef unsigned short u16;
typedef __attribute__((ext_vector_type(8))) short bf16x8;   // 8 bf16 (4 VGPRs)
typedef __attribute__((ext_vector_type(4))) float f32x4;
typedef __attribute__((ext_vector_type(4))) float float4v;
typedef __attribute__((ext_vector_type(4))) u16 u16x4;
typedef __attribute__((ext_vector_type(8))) u16 u16x8;

typedef __attribute__((address_space(3))) void lds_void;
typedef const __attribute__((address_space(1))) void gbl_void;

__device__ __forceinline__ void gload_lds16(const void* g, void* l) {
  __builtin_amdgcn_global_load_lds((gbl_void*)(uintptr_t)g,
                                   (lds_void*)(uint32_t)(uintptr_t)l, 16, 0, 0);
}

__device__ __forceinline__ u16 f2bf(float f) {
  union { float f; uint32_t u; } v; v.f = f;
  uint32_t r = v.u + 0x7FFFu + ((v.u >> 16) & 1u);
  return (u16)(r >> 16);
}
__device__ __forceinline__ float bf2f(u16 h) {
  union { uint32_t u; float f; } v; v.u = ((uint32_t)h) << 16;
  return v.f;
}

// raw barrier (NOT __syncthreads: that drains vmcnt(0) and kills the pipeline)
#define BAR() do { asm volatile("" ::: "memory"); __builtin_amdgcn_s_barrier(); asm volatile("" ::: "memory"); } while (0)
#define VMCNT(n) asm volatile("s_waitcnt vmcnt(" #n ")" ::: "memory")

// ---------- conversions ----------
__global__ __launch_bounds__(256) void k_conv_x(const float* __restrict__ x, u16* __restrict__ o) {
  size_t idx = (size_t)blockIdx.x * 256 + threadIdx.x;
  float4v xv = *(const float4v*)(x + idx * 4);
  u16x4 r;
#pragma unroll
  for (int e = 0; e < 4; ++e) r[e] = f2bf(xv[e]);
  *(u16x4*)(o + idx * 4) = r;
}

// LDS-tiled transpose+convert: out[n][k] = src[k][n], 64x64 tiles
__device__ __forceinline__ void ttile(const float* __restrict__ src, int ldw, int nb,
                                      int k0, int n0out, u16* __restrict__ out, int tid,
                                      float (*Lt)[68]) {
  int kr = tid >> 4, nc = (tid & 15) * 4;
#pragma unroll
  for (int s = 0; s < 4; ++s) {
    float4v v = *(const float4v*)(src + (size_t)(k0 + kr + 16 * s) * ldw + nb + nc);
#pragma unroll
    for (int e = 0; e < 4; ++e) Lt[kr + 16 * s][nc + e] = v[e];
  }
  __syncthreads();
  int nr = tid & 31, kc = (tid >> 5) * 8;
#pragma unroll
  for (int s2 = 0; s2 < 2; ++s2) {
    int n = nr + 32 * s2;
    u16x8 o;
#pragma unroll
    for (int e = 0; e < 8; ++e) o[e] = f2bf(Lt[kc + e][n]);
    *(u16x8*)(out + (size_t)(n0out + n) * 2048 + k0 + kc) = o;
  }
}

__global__ __launch_bounds__(256) void k_wt_qkv(const float* __restrict__ Wq, const float* __restrict__ Wk,
                                                const float* __restrict__ Wv, u16* __restrict__ wt) {
  __shared__ float Lt[64][68];
  const int n0 = blockIdx.x * 64, k0 = blockIdx.y * 64;
  const float* src; int ldw, nb;
  if (n0 < 2048)      { src = Wq; ldw = 2048; nb = n0; }
  else if (n0 < 2560) { src = Wk; ldw = 512;  nb = n0 - 2048; }
  else                { src = Wv; ldw = 512;  nb = n0 - 2560; }
  ttile(src, ldw, nb, k0, n0, wt, threadIdx.x, Lt);
}

__global__ __launch_bounds__(256) void k_wo_t(const float* __restrict__ Wo, u16* __restrict__ wt) {
  __shared__ float Lt[64][68];
  ttile(Wo, 2048, blockIdx.x * 64, blockIdx.y * 64, blockIdx.x * 64, wt, threadIdx.x, Lt);
}

__global__ __launch_bounds__(256) void k_cs(float* __restrict__ cst) {
  int idx = blockIdx.x * 256 + threadIdx.x;   // 131072
  int t = idx >> 6, d = idx & 63;
  float inv = expf(-(float)d * (1.0f / 64.0f) * 9.2103403719761836f);
  float f = (float)t * inv;
  float s, c;
  sincosf(f, &s, &c);
  cst[idx * 2] = c;
  cst[idx * 2 + 1] = s;
}

// RoPE in place, x8 vectorized; folds 1/sqrt(HD) into q heads
__global__ __launch_bounds__(256) void k_rope(u16* __restrict__ qkv, const float* __restrict__ cst) {
  int idx = blockIdx.x * 256 + threadIdx.x;   // 1,310,720
  int token = idx / 160;
  int rem = idx - token * 160;
  int hd = rem >> 3, oct = rem & 7;
  int col = ((hd < 16) ? hd * 128 : 2048 + (hd - 16) * 128) + oct * 8;
  size_t base = (size_t)token * LDQKV + col;
  int t = token & (T_ - 1);
  float sc = (hd < 16) ? 0.08838834764831845f : 1.0f;
  u16x8 a = *(const u16x8*)(qkv + base);
  u16x8 b2 = *(const u16x8*)(qkv + base + 64);
  const float* cp = cst + (size_t)(t * 64 + oct * 8) * 2;
  u16x8 ra, rb;
#pragma unroll
  for (int e = 0; e < 8; ++e) {
    float c = cp[e * 2], s = cp[e * 2 + 1];
    float x1 = bf2f(a[e]), x2 = bf2f(b2[e]);
    ra[e] = f2bf((x1 * c - x2 * s) * sc);
    rb[e] = f2bf((x1 * s + x2 * c) * sc);
  }
  *(u16x8*)(qkv + base) = ra;
  *(u16x8*)(qkv + base + 64) = rb;
}

// ---------- 256xBN 4-phase GEMM: C[M][N] = A[M][K] * Bt[N][K]^T ----------
// BN = NF*64. 8 waves (2M x 4N), per-wave out 128 x NF*16. BK=64, dbuf LDS.
// Per phase: {ds_read subtile; stage-issue; setprio(1); MFMA; setprio(0); [gate]; BAR}.
// Only ONE barrier per phase (4/tile): every ds_read is consumed by an MFMA before
// the closing BAR, so the compiler's register-dep lgkmcnt waits guarantee reads are
// drained at each barrier (no blanket LGKM0 -> compiler uses fine-grained counts).
// Staging (64-row units, 1 gload/thread/unit):
//   ph0: A0,A1(t+1)  ph1: A2,A3(t+1)  ph2: B0,B1(t+2)  ph3: B2[,B3](t+2)
// vmcnt FIFO (per wave): start-of-tile outstanding = B(t+1):NF; gate at ph3 end
// VMCNT(NF) drains B(t+1)+A(t+1), leaves B(t+2):NF. Tail: VMCNT(0).
// Overwrite safety: stage A(t+1) hits other buffer (A(t-1) reads drained by t-1 ph3
// BAR); stage B(t+2) hits current B region (bb reads drained by ph0's closing BAR).
template<int OUTF32, int NF>
__global__ __launch_bounds__(512, 1) void k_gemm8(const u16* __restrict__ A, const u16* __restrict__ Bt,
                                                  void* __restrict__ Cout, int M, int N, int K, int nbx) {
  constexpr int BUFE = 16384 + NF * 4096;   // u16 elems per buffer (A 256x64 + B NF*64x64)
  __shared__ __attribute__((aligned(16))) u16 lds[2 * BUFE];
  const int tid = threadIdx.x, lane = tid & 63;
  const int w = tid >> 6, wm = w >> 2, wn = w & 3;
  const int l15 = lane & 15, lhi = lane >> 4;
  const int nwg = gridDim.x, cpx = nwg >> 3;
  const int wg = (blockIdx.x & 7) * cpx + (blockIdx.x >> 3);
  const int bx = wg % nbx, by = wg / nbx;
  const int m0 = by * 256, n0 = bx * (NF * 64);
  const int NT = K >> 6;

  auto STAGE = [&](int u, int tt) {   // u 0..3 = A units; 4..3+NF = B units (64 rows each)
    const u16* src = (u < 4) ? A : Bt;
    const int r0 = (u < 4) ? (m0 + u * 64) : (n0 + (u - 4) * 64);
    u16* dst = lds + (tt & 1) * BUFE + u * 4096;
    int row = tid >> 3, kc = tid & 7;
    gload_lds16(src + (size_t)(r0 + row) * K + tt * 64 + ((kc ^ (row & 7)) * 8), dst + tid * 8);
  };
  auto RA = [&](const u16* buf, int mf, int ks) -> bf16x8 {
    return *(const bf16x8*)&buf[(wm * 128 + mf * 16 + l15) * 64 + (((ks * 4 + lhi) ^ (l15 & 7)) * 8)];
  };
  auto RB = [&](const u16* buf, int nf, int ks) -> bf16x8 {
    return *(const bf16x8*)&buf[16384 + (wn * (NF * 16) + nf * 16 + l15) * 64 + (((ks * 4 + lhi) ^ (l15 & 7)) * 8)];
  };

  f32x4 acc[8][NF];
#pragma unroll
  for (int i = 0; i < 8; ++i)
#pragma unroll
    for (int j = 0; j < NF; ++j) acc[i][j] = (f32x4){0.f, 0.f, 0.f, 0.f};

  // prologue: stage tile0 fully + B(t1); drain tile0, leave B(t1) in flight
#pragma unroll
  for (int u = 0; u < 4 + NF; ++u) STAGE(u, 0);
#pragma unroll
  for (int u = 4; u < 4 + NF; ++u) STAGE(u, 1);
  if constexpr (NF == 3) { VMCNT(3); } else { VMCNT(4); }
  BAR();

  for (int t = 0; t < NT; ++t) {
    const u16* buf = lds + (t & 1) * BUFE;
    const bool hasN1 = (t + 1 < NT), hasN2 = (t + 2 < NT);
    bf16x8 bb[NF][2], aa[2][2];
    // MFMA quad h: acc rows h*2,h*2+1 x all nf, ks-outer (indep distance 2*NF)
    auto MQ = [&](int h) {
#pragma unroll
      for (int ks = 0; ks < 2; ++ks)
#pragma unroll
        for (int mi = 0; mi < 2; ++mi)
#pragma unroll
          for (int nf = 0; nf < NF; ++nf)
            acc[h * 2 + mi][nf] = __builtin_amdgcn_mfma_f32_16x16x32_bf16(
                aa[mi][ks], bb[nf][ks], acc[h * 2 + mi][nf], 0, 0, 0);
    };
    // ---- ph0: read bb(all) + af[0-1]; stage A0,A1(t+1)
#pragma unroll
    for (int nf = 0; nf < NF; ++nf) { bb[nf][0] = RB(buf, nf, 0); bb[nf][1] = RB(buf, nf, 1); }
#pragma unroll
    for (int ks = 0; ks < 2; ++ks) { aa[0][ks] = RA(buf, 0, ks); aa[1][ks] = RA(buf, 1, ks); }
    if (hasN1) { STAGE(0, t + 1); STAGE(1, t + 1); }
    __builtin_amdgcn_s_setprio(1);
    MQ(0);
    __builtin_amdgcn_s_setprio(0);
    BAR();
    // ---- ph1: read af[2-3]; stage A2,A3(t+1)
#pragma unroll
    for (int ks = 0; ks < 2; ++ks) { aa[0][ks] = RA(buf, 2, ks); aa[1][ks] = RA(buf, 3, ks); }
    if (hasN1) { STAGE(2, t + 1); STAGE(3, t + 1); }
    __builtin_amdgcn_s_setprio(1);
    MQ(1);
    __builtin_amdgcn_s_setprio(0);
    BAR();
    // ---- ph2: read af[4-5]; stage B0,B1(t+2)
#pragma unroll
    for (int ks = 0; ks < 2; ++ks) { aa[0][ks] = RA(buf, 4, ks); aa[1][ks] = RA(buf, 5, ks); }
    if (hasN2) { STAGE(4, t + 2); STAGE(5, t + 2); }
    __builtin_amdgcn_s_setprio(1);
    MQ(2);
    __builtin_amdgcn_s_setprio(0);
    BAR();
    // ---- ph3: read af[6-7]; stage B2..(t+2); gate; barrier
#pragma unroll
    for (int ks = 0; ks < 2; ++ks) { aa[0][ks] = RA(buf, 6, ks); aa[1][ks] = RA(buf, 7, ks); }
    if (hasN2) {
      STAGE(6, t + 2);
      if constexpr (NF == 4) STAGE(7, t + 2);
    }
    __builtin_amdgcn_s_setprio(1);
    MQ(3);
    __builtin_amdgcn_s_setprio(0);
    if (hasN2) {
      if constexpr (NF == 3) { VMCNT(3); } else { VMCNT(4); }
    } else {
      VMCNT(0);
    }
    BAR();
  }

  // epilogue: rows m0+wm*128+mf*16+lhi*4+r, cols n0+wn*(NF*16)+nf*16+l15
#pragma unroll
  for (int mf = 0; mf < 8; ++mf) {
#pragma unroll
    for (int nf = 0; nf < NF; ++nf) {
      int col = n0 + wn * (NF * 16) + nf * 16 + l15;
#pragma unroll
      for (int r = 0; r < 4; ++r) {
        int row = m0 + wm * 128 + mf * 16 + lhi * 4 + r;
        float v = acc[mf][nf][r];
        if (OUTF32) ((float*)Cout)[(size_t)row * N + col] = v;
        else        ((u16*)Cout)[(size_t)row * N + col] = f2bf(v);
      }
    }
  }
}

// ---------- windowed flash attention (swizzled, conflict-free; unchanged) ----------
__global__ __launch_bounds__(256) void k_attn(const u16* __restrict__ qkv, u16* __restrict__ y) {
  const int bid = blockIdx.x;
  const int qt = bid & 31, h = (bid >> 5) & 15, b = bid >> 9;
  const int i0 = qt * 64;
  const size_t tb = (size_t)b * T_ * LDQKV;
  const u16* qb = qkv + tb + h * HD;
  const u16* kb = qkv + tb + 2048 + (h >> 2) * HD;
  const u16* vb = kb + 512;
  __shared__ __attribute__((aligned(16))) u16 smem[20480];   // 40 KB
  u16* Ks = smem;
  u16* Vt = smem + 8192;
  u16* Psw = smem + 16384;
  u16* Qs = smem;
  const int tid = threadIdx.x, lane = tid & 63, w = tid >> 6;
  const int l15 = lane & 15, lhi = lane >> 4;
  u16* Ps = Psw + w * 1024;

#pragma unroll
  for (int it = 0; it < 4; ++it) {
    int c = it * 256 + tid, row = c >> 4, kc = (c & 15) ^ (row & 7);
    gload_lds16(qb + (size_t)(i0 + row) * LDQKV + kc * 8, &Qs[(it * 256 + w * 64) * 8]);
  }
  __syncthreads();
  bf16x8 qf[4];
#pragma unroll
  for (int ks = 0; ks < 4; ++ks) {
    int row = w * 16 + l15;
    int kc = (ks * 4 + lhi) ^ (row & 7);
    qf[ks] = *(const bf16x8*)&Qs[(row * 16 + kc) * 8];
  }
  __syncthreads();

  f32x4 o[8];
#pragma unroll
  for (int dt = 0; dt < 8; ++dt) o[dt] = (f32x4){0.f, 0.f, 0.f, 0.f};
  float mrun[4], lrun[4];
#pragma unroll
  for (int r = 0; r < 4; ++r) { mrun[r] = -1e30f; lrun[r] = 0.f; }

  const int jb0 = (i0 >= 256) ? (i0 - 256) : 0;
  for (int jb = jb0; jb <= i0; jb += 64) {
#pragma unroll
    for (int it = 0; it < 4; ++it) {
      int c = it * 256 + tid, row = c >> 4, kc = (c & 15) ^ (row & 7);
      gload_lds16(kb + (size_t)(jb + row) * LDQKV + kc * 8, &Ks[(it * 256 + w * 64) * 8]);
    }
#pragma unroll
    for (int it = 0; it < 4; ++it) {
      int chunk = it * 256 + tid, row = chunk >> 4, dc = chunk & 15;
      u16x8 vv = *(const u16x8*)(vb + (size_t)(jb + row) * LDQKV + dc * 8);
#pragma unroll
      for (int e = 0; e < 8; ++e) {
        int d = dc * 8 + e;
        int s = (dc ^ e) & 7;
        Vt[d * 64 + (row ^ (s << 3))] = vv[e];
      }
    }
    __syncthreads();

    f32x4 s[4];
#pragma unroll
    for (int t = 0; t < 4; ++t) {
      s[t] = (f32x4){0.f, 0.f, 0.f, 0.f};
#pragma unroll
      for (int ks = 0; ks < 4; ++ks) {
        int row = t * 16 + l15;
        int kc = (ks * 4 + lhi) ^ (row & 7);
        bf16x8 kf = *(const bf16x8*)&Ks[(row * 16 + kc) * 8];
        s[t] = __builtin_amdgcn_mfma_f32_16x16x32_bf16(qf[ks], kf, s[t], 0, 0, 0);
      }
    }

    const int irow0 = i0 + w * 16 + lhi * 4;
    float rmax[4];
#pragma unroll
    for (int r = 0; r < 4; ++r) rmax[r] = -1e30f;
#pragma unroll
    for (int t = 0; t < 4; ++t) {
      int j = jb + t * 16 + l15;
#pragma unroll
      for (int r = 0; r < 4; ++r) {
        int i = irow0 + r;
        float sv = s[t][r];
        sv = (j <= i && j + 256 >= i) ? sv : -1e30f;
        s[t][r] = sv;
        rmax[r] = fmaxf(rmax[r], sv);
      }
    }
#pragma unroll
    for (int r = 0; r < 4; ++r) {
#pragma unroll
      for (int off = 1; off < 16; off <<= 1)
        rmax[r] = fmaxf(rmax[r], __shfl_xor(rmax[r], off));
    }
    float sf[4], psum[4];
#pragma unroll
    for (int r = 0; r < 4; ++r) {
      float mn = fmaxf(mrun[r], rmax[r]);
      sf[r] = __expf(mrun[r] - mn);
      mrun[r] = mn;
      psum[r] = 0.f;
    }
#pragma unroll
    for (int t = 0; t < 4; ++t) {
#pragma unroll
      for (int r = 0; r < 4; ++r) {
        float p = __expf(s[t][r] - mrun[r]);
        psum[r] += p;
        int q = lhi * 4 + r;
        int k = t * 16 + l15;
        Ps[q * 64 + (k ^ ((q & 7) << 3))] = f2bf(p);
      }
    }
#pragma unroll
    for (int r = 0; r < 4; ++r) {
#pragma unroll
      for (int off = 1; off < 16; off <<= 1)
        psum[r] += __shfl_xor(psum[r], off);
      lrun[r] = lrun[r] * sf[r] + psum[r];
    }
#pragma unroll
    for (int dt = 0; dt < 8; ++dt)
#pragma unroll
      for (int r = 0; r < 4; ++r)
        o[dt][r] = o[dt][r] * sf[r];

    bf16x8 pf[2];
#pragma unroll
    for (int ks2 = 0; ks2 < 2; ++ks2)
      pf[ks2] = *(const bf16x8*)&Ps[l15 * 64 + ((ks2 * 32 + lhi * 8) ^ ((l15 & 7) << 3))];
#pragma unroll
    for (int dt = 0; dt < 8; ++dt) {
#pragma unroll
      for (int ks2 = 0; ks2 < 2; ++ks2) {
        int d = dt * 16 + l15;
        int s2 = ((d >> 3) ^ (d & 7)) & 7;
        bf16x8 vf = *(const bf16x8*)&Vt[d * 64 + ((ks2 * 32 + lhi * 8) ^ (s2 << 3))];
        o[dt] = __builtin_amdgcn_mfma_f32_16x16x32_bf16(pf[ks2], vf, o[dt], 0, 0, 0);
      }
    }
    __syncthreads();
  }

#pragma unroll
  for (int dt = 0; dt < 8; ++dt) {
#pragma unroll
    for (int r = 0; r < 4; ++r) {
      int i = i0 + w * 16 + lhi * 4 + r;
      float v = o[dt][r] / lrun[r];
      y[((size_t)b * T_ + i) * C_ + h * HD + dt * 16 + l15] = f2bf(v);
    }
  }
}

extern "C" void kernel_launch(void* const* d_in, const int* in_sizes, int n_in,
                              void* d_out, int out_size, void* d_ws, size_t ws_size,
                              hipStream_t stream) {
  const float* x  = (const float*)d_in[0];
  const float* Wq = (const float*)d_in[1];
  const float* Wk = (const float*)d_in[2];
  const float* Wv = (const float*)d_in[3];
  const float* Wo = (const float*)d_in[4];
  char* ws = (char*)d_ws;
  u16* x_bf   = (u16*)(ws);                 // 33,554,432 B (reused as y after GEMM1)
  u16* wt_qkv = (u16*)(ws + 33554432);      // 12,582,912 B
  u16* wo_t   = (u16*)(ws + 46137344);      //  8,388,608 B
  u16* qkv    = (u16*)(ws + 54525952);      // 50,331,648 B
  float* cst  = (float*)(ws + 104857600);   //  1,048,576 B
  u16* ybuf = x_bf;

  k_conv_x <<<16384, 256, 0, stream>>>(x, x_bf);
  k_wt_qkv <<<dim3(48, 32), 256, 0, stream>>>(Wq, Wk, Wv, wt_qkv);
  k_wo_t   <<<dim3(32, 32), 256, 0, stream>>>(Wo, wo_t);
  k_cs     <<<512, 256, 0, stream>>>(cst);

  // GEMM1: BN=192 -> grid 16x32 = 512 blocks = 2 exact rounds of 3/4-size blocks
  k_gemm8<0, 3><<<512, 512, 0, stream>>>(x_bf, wt_qkv, (void*)qkv, 8192, 3072, 2048, 16);

  k_rope   <<<5120, 256, 0, stream>>>(qkv, cst);
  k_attn   <<<2048, 256, 0, stream>>>(qkv, ybuf);

  // GEMM2: BN=256 -> grid 256 = 1 exact round
  k_gemm8<1, 4><<<256, 512, 0, stream>>>(ybuf, wo_t, d_out, 8192, 2048, 2048, 8);
}